// Round 3
// baseline (103.605 us; speedup 1.0000x reference)
//
#include <hip/hip_runtime.h>

// 4-level db4 wavedec (symmetric mode) + 6 stats per band.
// One block of 512 threads per signal. Levels: 16384 -> 8195 -> 4101 -> 2054 -> 1030.
//
// V4 (vs V3 ping-pong @90us): single in-place LDS buffer -> 4 blocks/CU.
//  - decimation writes trail reads: quad k writes A[4k..4k+3], reads
//    A[8k-8..8k+11]; per 512-quad chunk use {read+compute c} bar {write c || read c+1}.
//    Disjointness: writes [2048c..2048c+2047] vs same-interval reads
//    [4096(c+1)-8 ..]; sym-folds hit the never-written high region. Race-free.
//  - LDS 50KB -> 34.4KB (A[8196]+red) -> 4 blocks/CU = 32 waves/CU (HW cap),
//    8 waves/SIMD. launch_bounds(512,8) caps VGPR at 64 (est. use ~55).
//  - band_reduce: 5x ds_swizzle (xor 1,2,4,8,16) butterfly within 32-lane
//    halves; 16 half-wave partials to red; xor-32 moved to the finalize pass.
//  - quad-per-thread + fused cA4 stats + sign-bit zc kept from V3.
// Band order: [cA4, cD4, cD3, cD2, cD1] x [mean_abs, std, rms, max, energy, zc].

#define T0 16384
#define BLK 512

// Reversed db4 decomposition filters (lax correlation == pywt convolution).
constexpr float FLO[8] = {
     0.23037781330885523f,  0.7148465705525415f,   0.6308807679295904f,
    -0.02798376941698385f, -0.18703481171888114f,  0.030841381835986965f,
     0.032883011666982945f, -0.010597401784997278f };
constexpr float FHI[8] = {
    -0.010597401784997278f, -0.032883011666982945f, 0.030841381835986965f,
     0.18703481171888114f,  -0.02798376941698385f,  -0.6308807679295904f,
     0.7148465705525415f,   -0.23037781330885523f };

// symmetric extension fold: ext index t -> valid index (single fold suffices).
__device__ __forceinline__ float getsym(const float* __restrict__ s, int t, int L) {
    if (t < 0) t = -1 - t;
    else if (t >= L) t = 2 * L - 1 - t;
    return s[t];
}

// 1 if sign bits differ (zero-crossing). Matches sign()-diff for nonzero data.
__device__ __forceinline__ float zcstep(float p, float q) {
    return ((__float_as_int(p) ^ __float_as_int(q)) < 0) ? 1.f : 0.f;
}

// Butterfly reduce within 32-lane halves via single-inst ds_swizzle
// (xor 1,2,4,8,16); lanes 0 mod 32 write half-wave partials to
// red[band*16 + half]. The cross-row (xor 32) step is folded into finalize.
// NO barrier here (deferred).
__device__ __forceinline__ void band_reduce(float sabs, float ssum, float ssq,
                                            float smax, float zc,
                                            int band, float* __restrict__ red) {
#define SWZF(v, PAT) __int_as_float(__builtin_amdgcn_ds_swizzle(__float_as_int(v), PAT))
#define RSTEP(PAT) \
    sabs += SWZF(sabs, PAT); \
    ssum += SWZF(ssum, PAT); \
    ssq  += SWZF(ssq,  PAT); \
    smax  = fmaxf(smax, SWZF(smax, PAT)); \
    zc   += SWZF(zc,   PAT);
    RSTEP(0x041F) RSTEP(0x081F) RSTEP(0x101F) RSTEP(0x201F) RSTEP(0x401F)
#undef RSTEP
#undef SWZF
    if ((threadIdx.x & 31) == 0) {
        float* r = red + (band * 16 + ((int)threadIdx.x >> 5)) * 5;
        r[0] = sabs; r[1] = ssum; r[2] = ssq; r[3] = smax; r[4] = zc;
    }
}

// Load the 20-float window for quad k: v[j] = src_ext[8k-8+j]. Fast path is
// 5x float4 (16B aligned); boundary threads take the folded scalar path
// (only v[2..17] are consumed).
__device__ __forceinline__ void load_win(const float* __restrict__ src, int L, int k,
                                         float* __restrict__ v) {
    const int w = 8 * k - 8;
    if (w >= 0 && w + 20 <= L) {
        #pragma unroll
        for (int q = 0; q < 5; ++q) {
            const float4 t = *reinterpret_cast<const float4*>(src + w + 4 * q);
            v[4*q+0] = t.x; v[4*q+1] = t.y; v[4*q+2] = t.z; v[4*q+3] = t.w;
        }
    } else {
        #pragma unroll
        for (int j = 2; j < 18; ++j) v[j] = getsym(src, w + j, L);
    }
}

// a[0..3], d[0..4] (+a[4] if LAST) for one quad from window v[2..17].
template<bool LAST>
__device__ __forceinline__ void quad_dots(const float* __restrict__ v,
                                          float* __restrict__ a, float* __restrict__ d) {
    #pragma unroll
    for (int i = 0; i < 5; ++i) { a[i] = 0.f; d[i] = 0.f; }
    #pragma unroll
    for (int i = 0; i < 4; ++i) {
        #pragma unroll
        for (int m = 0; m < 8; ++m) {
            a[i] = fmaf(v[2*i+2+m], FLO[m], a[i]);
            d[i] = fmaf(v[2*i+2+m], FHI[m], d[i]);
        }
    }
    #pragma unroll
    for (int m = 0; m < 8; ++m) {
        d[4] = fmaf(v[10+m], FHI[m], d[4]);
        if constexpr (LAST) a[4] = fmaf(v[10+m], FLO[m], a[4]);
    }
}

// Level 1: global x -> LDS A (no read/write hazard, no internal barriers).
__device__ void dwt_l1(const float* __restrict__ x, float* __restrict__ A,
                       float* __restrict__ red) {
    float sabs = 0.f, ssum = 0.f, ssq = 0.f, smax = 0.f, zc = 0.f;
    const int L = T0;                   // o = 8195, nq_main = 2048 (exact)
    for (int k = (int)threadIdx.x; k < 2048; k += BLK) {
        float v[20], a[5], d[5];
        load_win(x, L, k, v);
        quad_dots<false>(v, a, d);
        *reinterpret_cast<float4*>(A + 4 * k) = make_float4(a[0], a[1], a[2], a[3]);
        #pragma unroll
        for (int i = 0; i < 4; ++i) {
            const float ad = fabsf(d[i]);
            sabs += ad; ssum += d[i]; ssq = fmaf(d[i], d[i], ssq);
            smax = fmaxf(smax, ad);
            zc += zcstep(d[i], d[i + 1]);
        }
    }
    if (threadIdx.x == BLK - 1) {       // tail quad k=2048: outputs 8192..8194
        const int k = 2048;
        float v[20], a[5], d[5];
        #pragma unroll
        for (int j = 2; j < 18; ++j) v[j] = getsym(x, 8 * k - 8 + j, L);
        quad_dots<false>(v, a, d);
        #pragma unroll
        for (int m = 0; m < 8; ++m) a[4] = fmaf(v[10 + m], FLO[m], a[4]);
        #pragma unroll
        for (int i = 0; i < 4; ++i) {
            const int p = 4 * k + i;
            if (p < 8195) {
                A[p] = a[i];
                const float ad = fabsf(d[i]);
                sabs += ad; ssum += d[i]; ssq = fmaf(d[i], d[i], ssq);
                smax = fmaxf(smax, ad);
                if (p + 1 < 8195) zc += zcstep(d[i], d[i + 1]);
            }
        }
    }
    band_reduce(sabs, ssum, ssq, smax, zc, 4, red);
}

// In-place level in buffer A: cA_next overwrites A[0..o), source is A[0..L).
// Phases: {read+compute chunk c} bar {write c || read c+1}. LAST: stats only.
template<bool LAST, int L, int o, int DBAND>
__device__ __forceinline__ void dwt_ip(float* __restrict__ A, float* __restrict__ red) {
    float sabs = 0.f, ssum = 0.f, ssq = 0.f, smax = 0.f, zc = 0.f;       // cD
    float sabsA = 0.f, ssumA = 0.f, ssqA = 0.f, smaxA = 0.f, zcA = 0.f;  // cA (LAST)
    constexpr int NQ  = (o - 1) >> 2;             // unguarded quads
    constexpr int NCH = (NQ + BLK - 1) / BLK;     // 3 / 2 / 1
    const int tid = (int)threadIdx.x;

    float ap[4];  int wk = -1;                    // pending main write
    float tq[4];  bool tw = false;                // pending tail write (thr 511)

    #pragma unroll
    for (int c = 0; c < NCH; ++c) {
        const int k = c * BLK + tid;
        wk = -1;
        if (k < NQ) {
            float v[20], a[5], d[5];
            load_win(A, L, k, v);
            quad_dots<LAST>(v, a, d);
            #pragma unroll
            for (int i = 0; i < 4; ++i) {
                const float ad = fabsf(d[i]);
                sabs += ad; ssum += d[i]; ssq = fmaf(d[i], d[i], ssq);
                smax = fmaxf(smax, ad);
                zc += zcstep(d[i], d[i + 1]);
                if constexpr (LAST) {
                    const float aa = fabsf(a[i]);
                    sabsA += aa; ssumA += a[i]; ssqA = fmaf(a[i], a[i], ssqA);
                    smaxA = fmaxf(smaxA, aa);
                    zcA += zcstep(a[i], a[i + 1]);
                }
            }
            ap[0] = a[0]; ap[1] = a[1]; ap[2] = a[2]; ap[3] = a[3];
            wk = k;
        }
        if (c == NCH - 1 && tid == BLK - 1) {     // tail quad k=NQ (guarded)
            float v[20], a[5], d[5];
            #pragma unroll
            for (int j = 2; j < 18; ++j) v[j] = getsym(A, 8 * NQ - 8 + j, L);
            quad_dots<true>(v, a, d);             // full 5 a-dots (cheap, cold)
            #pragma unroll
            for (int i = 0; i < 4; ++i) {
                const int p = 4 * NQ + i;
                if (p < o) {
                    const float ad = fabsf(d[i]);
                    sabs += ad; ssum += d[i]; ssq = fmaf(d[i], d[i], ssq);
                    smax = fmaxf(smax, ad);
                    if (p + 1 < o) zc += zcstep(d[i], d[i + 1]);
                    if constexpr (LAST) {
                        const float aa = fabsf(a[i]);
                        sabsA += aa; ssumA += a[i]; ssqA = fmaf(a[i], a[i], ssqA);
                        smaxA = fmaxf(smaxA, aa);
                        if (p + 1 < o) zcA += zcstep(a[i], a[i + 1]);
                    }
                }
                tq[i] = a[i];
            }
            tw = true;
        }
        if constexpr (!LAST) {
            __syncthreads();                      // chunk-c reads all complete
            if (wk >= 0)
                *reinterpret_cast<float4*>(A + 4 * wk) = make_float4(ap[0], ap[1], ap[2], ap[3]);
            if (tw) {
                #pragma unroll
                for (int i = 0; i < 4; ++i)
                    if (4 * NQ + i < o) A[4 * NQ + i] = tq[i];
                tw = false;
            }
        }
    }
    band_reduce(sabs, ssum, ssq, smax, zc, DBAND, red);
    if constexpr (LAST) band_reduce(sabsA, ssumA, ssqA, smaxA, zcA, 0, red);
}

__global__ void __launch_bounds__(BLK, 8)
wavelet_feat_kernel(const float* __restrict__ x, float* __restrict__ out) {
    __shared__ __align__(16) float A[8196];       // all cascade levels, in place
    __shared__ float red[5 * 16 * 5];             // [band][half-wave][stat]

    const int sig = blockIdx.x;
    const float* src0 = x + (size_t)sig * T0;
    float* outp = out + (size_t)sig * 30;

    // band index: 0=cA4 1=cD4 2=cD3 3=cD2 4=cD1
    dwt_l1(src0, A, red);                         // L1: x -> A, cD1
    __syncthreads();
    dwt_ip<false, 8195, 4101, 3>(A, red);         // L2 in place, cD2
    __syncthreads();
    dwt_ip<false, 4101, 2054, 2>(A, red);         // L3 in place, cD3
    __syncthreads();
    dwt_ip<true,  2054, 1030, 1>(A, red);         // L4: cD4 + cA4 stats (no writes)
    __syncthreads();                              // red[] complete

    if (threadIdx.x < 5) {
        const int band = (int)threadIdx.x;
        float a = 0.f, s = 0.f, q = 0.f, m = 0.f, z = 0.f;
        #pragma unroll
        for (int h = 0; h < 16; ++h) {
            const float* r = red + (band * 16 + h) * 5;
            a += r[0]; s += r[1]; q += r[2]; m = fmaxf(m, r[3]); z += r[4];
        }
        const int o = (band <= 1) ? 1030 : (band == 2 ? 2054 : (band == 3 ? 4101 : 8195));
        const float inv  = 1.0f / (float)o;
        const float mean = s * inv;
        const float var  = q * inv - mean * mean;
        float* op = outp + band * 6;
        op[0] = a * inv;                  // mean_abs
        op[1] = sqrtf(fmaxf(var, 0.f));   // std (population)
        op[2] = sqrtf(q * inv);           // rms
        op[3] = m;                        // max_abs
        op[4] = q;                        // energy
        op[5] = z * inv;                  // zero-crossing rate
    }
}

extern "C" void kernel_launch(void* const* d_in, const int* in_sizes, int n_in,
                              void* d_out, int out_size, void* d_ws, size_t ws_size,
                              hipStream_t stream) {
    const float* x = (const float*)d_in[0];
    float* out = (float*)d_out;
    const int nsig = in_sizes[0] / T0;   // 64*64 = 4096
    hipLaunchKernelGGL(wavelet_feat_kernel, dim3(nsig), dim3(BLK), 0, stream, x, out);
}